// Round 4
// baseline (1334.275 us; speedup 1.0000x reference)
//
#include <hip/hip_runtime.h>
#include <math.h>

#define N_NODES 100000
#define N_EDGES 1600000
#define RREL 4
#define DDIM 128
#define KDIM 512      // RREL*DDIM
#define NKEY 400000   // N_NODES*RREL

typedef __bf16 bf16x8 __attribute__((ext_vector_type(8)));
typedef float f32x4 __attribute__((ext_vector_type(4)));

__device__ __forceinline__ float bflo(unsigned u){ return __builtin_bit_cast(float, u << 16); }
__device__ __forceinline__ float bfhi(unsigned u){ return __builtin_bit_cast(float, u & 0xffff0000u); }
__device__ __forceinline__ unsigned f2bf(float f){
  unsigned u = __builtin_bit_cast(unsigned, f);
  return (u + 0x7fffu + ((u >> 16) & 1u)) >> 16;   // RNE, finite inputs
}
__device__ __forceinline__ int iclamp(int v, int lo, int hi){
  return v < lo ? lo : (v > hi ? hi : v);
}

// ---------------- counting sort of edges by key = dst*4 + et ----------------

__global__ void hist_kernel(const int* __restrict__ dst, const int* __restrict__ et,
                            int* __restrict__ counts){
  int e = blockIdx.x * 256 + threadIdx.x;
  int key = iclamp(dst[e] * RREL + et[e], 0, NKEY - 1);
  atomicAdd(&counts[key], 1);
}

__global__ void scan_local(const int* __restrict__ in, int* __restrict__ out,
                           int* __restrict__ bsums, int K){
  __shared__ int s[1024];
  int t = threadIdx.x;
  int i = blockIdx.x * 1024 + t;
  int v = (i < K) ? in[i] : 0;
  s[t] = v; __syncthreads();
  for (int off = 1; off < 1024; off <<= 1){
    int x = (t >= off) ? s[t - off] : 0;
    __syncthreads();
    s[t] += x;
    __syncthreads();
  }
  if (i < K) out[i] = s[t] - v;           // exclusive within block
  if (t == 1023) bsums[blockIdx.x] = s[t];
}

__global__ void scan_sums(int* __restrict__ b, int nb){
  __shared__ int s[1024];
  int t = threadIdx.x;
  int v = (t < nb) ? b[t] : 0;
  s[t] = v; __syncthreads();
  for (int off = 1; off < 1024; off <<= 1){
    int x = (t >= off) ? s[t - off] : 0;
    __syncthreads();
    s[t] += x;
    __syncthreads();
  }
  if (t < nb) b[t] = s[t] - v;            // exclusive block prefix
}

__global__ void scan_add(int* __restrict__ out, int* __restrict__ cursor,
                         const int* __restrict__ bsums, int K, int total){
  int t = threadIdx.x;
  int i = blockIdx.x * 1024 + t;
  if (i < K){
    int v = out[i] + bsums[blockIdx.x];
    out[i] = v;
    cursor[i] = v;
  }
  if (i == 0) out[K] = total;
}

__global__ void scatter_kernel(const int* __restrict__ src, const int* __restrict__ dst,
                               const int* __restrict__ et, int* __restrict__ cursor,
                               int* __restrict__ ssrc){
  int e = blockIdx.x * 256 + threadIdx.x;
  int key = iclamp(dst[e] * RREL + et[e], 0, NKEY - 1);
  int p = atomicAdd(&cursor[key], 1);
  p = iclamp(p, 0, N_EDGES - 1);
  ssrc[p] = iclamp(src[e], 0, N_NODES - 1);
}

// ---------------- x (f32 [N,128]) -> packed bf16 pairs [N,64] uints ----------------

__global__ void convert_x(const float* __restrict__ x, unsigned* __restrict__ xb){
  int i = blockIdx.x * 256 + threadIdx.x;      // over N*64
  float2 v = *(const float2*)(x + (size_t)i * 2);
  xb[i] = f2bf(v.x) | (f2bf(v.y) << 16);
}

// ---------------- W (f32 [512][128]) -> Bt bf16 [128][512] ----------------

__global__ void transpose_w(const float* __restrict__ W, unsigned short* __restrict__ Bt){
  int idx = blockIdx.x * 256 + threadIdx.x;    // 65536
  int k = idx >> 7, n = idx & 127;
  Bt[n * KDIM + k] = (unsigned short)f2bf(W[idx]);
}

// ---------------- fused layer: per-(node,rel) mean -> @W -> tanh -> packed bf16 ----------------
// Block = 64 nodes, 4 waves; each wave owns 16 nodes end-to-end (no barrier).
// LDS tile per wave: 16 rows x 512 bf16, row stride 520 bf16 (260 uints).

#define ROWU 260   // uints per LDS row (520 bf16)

__global__ __launch_bounds__(256) void fused_layer(const unsigned* __restrict__ hin,
                                                   const int* __restrict__ ssrc,
                                                   const int* __restrict__ offs,
                                                   const __bf16* __restrict__ Bt,
                                                   unsigned short* __restrict__ hout){
  __shared__ unsigned s_tile[4 * 16 * ROWU];   // 66,560 B
  int tid = threadIdx.x;
  int w = tid >> 6, lane = tid & 63;
  int l15 = lane & 15, quad = lane >> 4;
  int wbase = w * (16 * ROWU);
  int n0w = blockIdx.x * 64 + w * 16;

  // ---- phase 1: aggregate means for this wave's 16 nodes into LDS ----
  for (int nl = 0; nl < 16; nl++){
    int n = n0w + nl;
    unsigned* srow = &s_tile[wbase + nl * ROWU];
    if (n < N_NODES){
      int ob = n * 4;
      #pragma unroll
      for (int r = 0; r < RREL; r++){
        int beg = iclamp(offs[ob + r], 0, N_EDGES);
        int end = iclamp(offs[ob + r + 1], beg, N_EDGES);
        float a0=0.f,a1=0.f,b0=0.f,b1=0.f,c0=0.f,c1=0.f,d0=0.f,d1=0.f;
        int i = beg;
        for (; i + 4 <= end; i += 4){
          int s0 = iclamp(ssrc[i],     0, N_NODES-1);
          int s1 = iclamp(ssrc[i + 1], 0, N_NODES-1);
          int s2 = iclamp(ssrc[i + 2], 0, N_NODES-1);
          int s3 = iclamp(ssrc[i + 3], 0, N_NODES-1);
          unsigned u0 = hin[s0 * 64 + lane];
          unsigned u1 = hin[s1 * 64 + lane];
          unsigned u2 = hin[s2 * 64 + lane];
          unsigned u3 = hin[s3 * 64 + lane];
          a0 += bflo(u0); a1 += bfhi(u0);
          b0 += bflo(u1); b1 += bfhi(u1);
          c0 += bflo(u2); c1 += bfhi(u2);
          d0 += bflo(u3); d1 += bfhi(u3);
        }
        for (; i < end; i++){
          int s0 = iclamp(ssrc[i], 0, N_NODES-1);
          unsigned u = hin[s0 * 64 + lane];
          a0 += bflo(u); a1 += bfhi(u);
        }
        int cnt = end - beg;
        float sc = (cnt > 0) ? 1.0f / (float)cnt : 0.0f;
        float m0 = (a0 + b0 + c0 + d0) * sc;
        float m1 = (a1 + b1 + c1 + d1) * sc;
        srow[r * 64 + lane] = f2bf(m0) | (f2bf(m1) << 16);
      }
    } else {
      #pragma unroll
      for (int r = 0; r < RREL; r++) srow[r * 64 + lane] = 0u;
    }
  }

  // ---- phase 2: C[16x128] = A[16x512] @ B[512x128], A from own LDS ----
  f32x4 acc[8];
  #pragma unroll
  for (int tc = 0; tc < 8; tc++) acc[tc] = (f32x4){0.f, 0.f, 0.f, 0.f};

  const unsigned* arow = &s_tile[wbase + l15 * ROWU];
  #pragma unroll 2
  for (int k0 = 0; k0 < KDIM; k0 += 32){
    bf16x8 af = *(const bf16x8*)(arow + (k0 >> 1) + quad * 4);
    #pragma unroll
    for (int tc = 0; tc < 8; tc++){
      bf16x8 bf = *(const bf16x8*)(Bt + (size_t)(tc * 16 + l15) * KDIM + k0 + quad * 8);
      acc[tc] = __builtin_amdgcn_mfma_f32_16x16x32_bf16(af, bf, acc[tc], 0, 0, 0);
    }
  }

  // ---- epilogue: tanh, store bf16. C layout: col=l15, row=quad*4+reg ----
  #pragma unroll
  for (int tc = 0; tc < 8; tc++){
    #pragma unroll
    for (int reg = 0; reg < 4; reg++){
      int n = n0w + quad * 4 + reg;
      if (n < N_NODES){
        float v = tanhf(acc[tc][reg]);
        hout[(size_t)n * 128 + tc * 16 + l15] = (unsigned short)f2bf(v);
      }
    }
  }
}

// ---------------- fused head: mean -> dot W3 (f32 [512][2]) -> softmax -> f32 out ----------------
// One wave per node; lane holds dims (2*lane, 2*lane+1) of each relation block.

__global__ void fused_head(const unsigned* __restrict__ h2,
                           const int* __restrict__ ssrc,
                           const int* __restrict__ offs,
                           const float* __restrict__ W3f,
                           float* __restrict__ out){
  int n = blockIdx.x * 4 + (threadIdx.x >> 6);
  int lane = threadIdx.x & 63;
  float dA = 0.f, dB = 0.f;
  int ob = n * 4;
  #pragma unroll
  for (int r = 0; r < RREL; r++){
    int beg = iclamp(offs[ob + r], 0, N_EDGES);
    int end = iclamp(offs[ob + r + 1], beg, N_EDGES);
    float a0=0.f,a1=0.f,b0=0.f,b1=0.f;
    int i = beg;
    for (; i + 2 <= end; i += 2){
      int s0 = iclamp(ssrc[i],     0, N_NODES-1);
      int s1 = iclamp(ssrc[i + 1], 0, N_NODES-1);
      unsigned u0 = h2[s0 * 64 + lane];
      unsigned u1 = h2[s1 * 64 + lane];
      a0 += bflo(u0); a1 += bfhi(u0);
      b0 += bflo(u1); b1 += bfhi(u1);
    }
    if (i < end){
      unsigned u = h2[iclamp(ssrc[i], 0, N_NODES-1) * 64 + lane];
      a0 += bflo(u); a1 += bfhi(u);
    }
    int cnt = end - beg;
    float sc = (cnt > 0) ? 1.0f / (float)cnt : 0.0f;
    float m0 = (a0 + b0) * sc, m1 = (a1 + b1) * sc;
    // dims k = r*128 + 2*lane and k+1; W3f[2k..2k+3] = {W3[k][0],W3[k][1],W3[k+1][0],W3[k+1][1]}
    float4 wv = *(const float4*)(W3f + r * 256 + lane * 4);
    dA += m0 * wv.x + m1 * wv.z;
    dB += m0 * wv.y + m1 * wv.w;
  }
  #pragma unroll
  for (int m = 32; m >= 1; m >>= 1){
    dA += __shfl_xor(dA, m);
    dB += __shfl_xor(dB, m);
  }
  if (lane == 0){
    float mx = fmaxf(dA, dB);
    float e0 = __expf(dA - mx), e1 = __expf(dB - mx);
    float inv = 1.0f / (e0 + e1);
    *(float2*)(out + 2 * n) = (float2){e0 * inv, e1 * inv};            // softmax [N,2]
    *(float2*)(out + 2 * N_NODES + 2 * n) = (float2){dA, dB};          // logits  [N,2]
  }
}

// ---------------- launch ----------------

extern "C" void kernel_launch(void* const* d_in, const int* in_sizes, int n_in,
                              void* d_out, int out_size, void* d_ws, size_t ws_size,
                              hipStream_t stream){
  const float* x  = (const float*)d_in[0];
  const int* ei   = (const int*)d_in[1];
  const int* et   = (const int*)d_in[2];
  const float* W1 = (const float*)d_in[3];
  const float* W2 = (const float*)d_in[4];
  const float* W3 = (const float*)d_in[5];
  float* out = (float*)d_out;
  const int* src = ei;
  const int* dst = ei + N_EDGES;

  // workspace layout: ~61 MB total
  char* p = (char*)d_ws;
  auto alloc = [&](size_t bytes) -> char* {
    char* q = p; p += (bytes + 63) & ~(size_t)63; return q;
  };
  int* counts = (int*)alloc((size_t)NKEY * 4);          // reused as cursor
  int* cursor = counts;
  int* offs   = (int*)alloc((size_t)(NKEY + 1) * 4);
  int* bsums  = (int*)alloc(1024 * 4);
  int* ssrc   = (int*)alloc((size_t)N_EDGES * 4);
  unsigned short* Bt = (unsigned short*)alloc((size_t)DDIM * KDIM * 2);
  unsigned short* h1 = (unsigned short*)alloc((size_t)N_NODES * DDIM * 2);
  unsigned short* h2 = (unsigned short*)alloc((size_t)N_NODES * DDIM * 2);
  unsigned* xb = (unsigned*)h2;   // x-as-bf16 lives in h2's slot (dead until layer-2 output)

  // sort edges by (dst, relation)
  hipMemsetAsync(counts, 0, (size_t)NKEY * 4, stream);
  hist_kernel<<<N_EDGES / 256, 256, 0, stream>>>(dst, et, counts);
  int nb = (NKEY + 1023) / 1024;  // 391
  scan_local<<<nb, 1024, 0, stream>>>(counts, offs, bsums, NKEY);
  scan_sums<<<1, 1024, 0, stream>>>(bsums, nb);
  scan_add<<<nb, 1024, 0, stream>>>(offs, cursor, bsums, NKEY, N_EDGES);
  scatter_kernel<<<N_EDGES / 256, 256, 0, stream>>>(src, dst, et, cursor, ssrc);

  int fgrid = (N_NODES + 63) / 64;  // 1563

  // layer 1: x -> packed bf16, agg -> @W1 -> tanh -> h1
  convert_x<<<(N_NODES * 64) / 256, 256, 0, stream>>>(x, xb);
  transpose_w<<<(DDIM * KDIM) / 256, 256, 0, stream>>>(W1, Bt);
  fused_layer<<<fgrid, 256, 0, stream>>>(xb, ssrc, offs, (const __bf16*)Bt, h1);
  // layer 2: h1 -> h2 (xb dead from here on)
  transpose_w<<<(DDIM * KDIM) / 256, 256, 0, stream>>>(W2, Bt);
  fused_layer<<<fgrid, 256, 0, stream>>>((const unsigned*)h1, ssrc, offs, (const __bf16*)Bt, h2);
  // layer 3 + softmax head (f32 out)
  fused_head<<<N_NODES / 4, 256, 0, stream>>>((const unsigned*)h2, ssrc, offs, W3, out);
}

// Round 5
// 816.946 us; speedup vs baseline: 1.6332x; 1.6332x over previous
//
#include <hip/hip_runtime.h>
#include <math.h>

#define N_NODES 100000
#define N_EDGES 1600000
#define RREL 4
#define DDIM 128
#define KDIM 512      // RREL*DDIM
#define NKEY 400000   // N_NODES*RREL

typedef __bf16 bf16x8 __attribute__((ext_vector_type(8)));
typedef float f32x4 __attribute__((ext_vector_type(4)));

__device__ __forceinline__ float bflo(unsigned u){ return __builtin_bit_cast(float, u << 16); }
__device__ __forceinline__ float bfhi(unsigned u){ return __builtin_bit_cast(float, u & 0xffff0000u); }
__device__ __forceinline__ unsigned f2bf(float f){
  unsigned u = __builtin_bit_cast(unsigned, f);
  return (u + 0x7fffu + ((u >> 16) & 1u)) >> 16;   // RNE, finite inputs
}
__device__ __forceinline__ int iclamp(int v, int lo, int hi){
  return v < lo ? lo : (v > hi ? hi : v);
}

// ---------------- counting sort of edges by key = dst*4 + et ----------------

__global__ void hist_kernel(const int* __restrict__ dst, const int* __restrict__ et,
                            int* __restrict__ counts){
  int e = blockIdx.x * 256 + threadIdx.x;
  int key = iclamp(dst[e] * RREL + et[e], 0, NKEY - 1);
  atomicAdd(&counts[key], 1);
}

__global__ void scan_local(const int* __restrict__ in, int* __restrict__ out,
                           int* __restrict__ bsums, int K){
  __shared__ int s[1024];
  int t = threadIdx.x;
  int i = blockIdx.x * 1024 + t;
  int v = (i < K) ? in[i] : 0;
  s[t] = v; __syncthreads();
  for (int off = 1; off < 1024; off <<= 1){
    int x = (t >= off) ? s[t - off] : 0;
    __syncthreads();
    s[t] += x;
    __syncthreads();
  }
  if (i < K) out[i] = s[t] - v;           // exclusive within block
  if (t == 1023) bsums[blockIdx.x] = s[t];
}

__global__ void scan_sums(int* __restrict__ b, int nb){
  __shared__ int s[1024];
  int t = threadIdx.x;
  int v = (t < nb) ? b[t] : 0;
  s[t] = v; __syncthreads();
  for (int off = 1; off < 1024; off <<= 1){
    int x = (t >= off) ? s[t - off] : 0;
    __syncthreads();
    s[t] += x;
    __syncthreads();
  }
  if (t < nb) b[t] = s[t] - v;            // exclusive block prefix
}

__global__ void scan_add(int* __restrict__ out, int* __restrict__ cursor,
                         const int* __restrict__ bsums, int K, int total){
  int t = threadIdx.x;
  int i = blockIdx.x * 1024 + t;
  if (i < K){
    int v = out[i] + bsums[blockIdx.x];
    out[i] = v;
    cursor[i] = v;
  }
  if (i == 0) out[K] = total;
}

__global__ void scatter_kernel(const int* __restrict__ src, const int* __restrict__ dst,
                               const int* __restrict__ et, int* __restrict__ cursor,
                               int* __restrict__ ssrc){
  int e = blockIdx.x * 256 + threadIdx.x;
  int key = iclamp(dst[e] * RREL + et[e], 0, NKEY - 1);
  int p = atomicAdd(&cursor[key], 1);
  p = iclamp(p, 0, N_EDGES - 1);
  ssrc[p] = iclamp(src[e], 0, N_NODES - 1);
}

// ---------------- x (f32 [N,128]) -> packed bf16 pairs [N,64] uints ----------------

__global__ void convert_x(const float* __restrict__ x, unsigned* __restrict__ xb){
  int i = blockIdx.x * 256 + threadIdx.x;      // over N*64
  float2 v = *(const float2*)(x + (size_t)i * 2);
  xb[i] = f2bf(v.x) | (f2bf(v.y) << 16);
}

// ---------------- W (f32 [512][128]) -> Bt bf16 [128][512] ----------------

__global__ void transpose_w(const float* __restrict__ W, unsigned short* __restrict__ Bt){
  int idx = blockIdx.x * 256 + threadIdx.x;    // 65536
  int k = idx >> 7, n = idx & 127;
  Bt[n * KDIM + k] = (unsigned short)f2bf(W[idx]);
}

// ---------------- fused layer: mean -> @W -> tanh, node-per-lane, zero LDS ----------------
// Wave handles 16 nodes; lane (l15,quad) owns node n0+l15, dims quad*8+t of each 32-wide
// K-window. All 16 segments of a relation aggregate concurrently (trip = max, not sum).
// Aggregation registers double as the MFMA A-fragment after scale+pack.

__global__ __launch_bounds__(256) void fused_layer(const unsigned* __restrict__ hin,
                                                   const int* __restrict__ ssrc,
                                                   const int* __restrict__ offs,
                                                   const __bf16* __restrict__ Bt,
                                                   unsigned short* __restrict__ hout){
  int tid = threadIdx.x;
  int w = tid >> 6, lane = tid & 63;
  int l15 = lane & 15, quad = lane >> 4;
  int n0w = blockIdx.x * 64 + w * 16;
  int n = n0w + l15;                     // this lane's node
  int valid = (n < N_NODES);

  f32x4 accC[8];
  #pragma unroll
  for (int tc = 0; tc < 8; tc++) accC[tc] = (f32x4){0.f, 0.f, 0.f, 0.f};

  #pragma unroll
  for (int r = 0; r < RREL; r++){
    int ob = valid ? (n * 4 + r) : 0;
    int beg = iclamp(offs[ob], 0, N_EDGES);
    int end = iclamp(offs[ob + 1], beg, N_EDGES);
    if (!valid){ beg = 0; end = 0; }

    float ac[32];
    #pragma unroll
    for (int j = 0; j < 32; j++) ac[j] = 0.f;

    int i = beg;
    int nxt = (i < end) ? ssrc[i] : 0;          // index prefetch
    while (i < end){
      int cur = iclamp(nxt, 0, N_NODES - 1);
      i++;
      nxt = (i < end) ? ssrc[i] : 0;
      const uint4* row = (const uint4*)(hin + (size_t)cur * 64 + quad * 4);
      uint4 u0 = row[0];                        // uints quad*4 + 0..3  (dims quad*8..+7, win 0)
      uint4 u1 = row[4];                        // +16 uints            (win 1)
      uint4 u2 = row[8];                        // +32                  (win 2)
      uint4 u3 = row[12];                       // +48                  (win 3)
      ac[ 0] += bflo(u0.x); ac[ 1] += bfhi(u0.x); ac[ 2] += bflo(u0.y); ac[ 3] += bfhi(u0.y);
      ac[ 4] += bflo(u0.z); ac[ 5] += bfhi(u0.z); ac[ 6] += bflo(u0.w); ac[ 7] += bfhi(u0.w);
      ac[ 8] += bflo(u1.x); ac[ 9] += bfhi(u1.x); ac[10] += bflo(u1.y); ac[11] += bfhi(u1.y);
      ac[12] += bflo(u1.z); ac[13] += bfhi(u1.z); ac[14] += bflo(u1.w); ac[15] += bfhi(u1.w);
      ac[16] += bflo(u2.x); ac[17] += bfhi(u2.x); ac[18] += bflo(u2.y); ac[19] += bfhi(u2.y);
      ac[20] += bflo(u2.z); ac[21] += bfhi(u2.z); ac[22] += bflo(u2.w); ac[23] += bfhi(u2.w);
      ac[24] += bflo(u3.x); ac[25] += bfhi(u3.x); ac[26] += bflo(u3.y); ac[27] += bfhi(u3.y);
      ac[28] += bflo(u3.z); ac[29] += bfhi(u3.z); ac[30] += bflo(u3.w); ac[31] += bfhi(u3.w);
    }
    int cnt = end - beg;
    float sc = (cnt > 0) ? 1.0f / (float)cnt : 0.0f;

    // 4 MFMA K-steps for this relation; A-frag packed from ac
    #pragma unroll
    for (int s = 0; s < 4; s++){
      uint4 pv;
      pv.x = f2bf(ac[s * 8 + 0] * sc) | (f2bf(ac[s * 8 + 1] * sc) << 16);
      pv.y = f2bf(ac[s * 8 + 2] * sc) | (f2bf(ac[s * 8 + 3] * sc) << 16);
      pv.z = f2bf(ac[s * 8 + 4] * sc) | (f2bf(ac[s * 8 + 5] * sc) << 16);
      pv.w = f2bf(ac[s * 8 + 6] * sc) | (f2bf(ac[s * 8 + 7] * sc) << 16);
      bf16x8 af = __builtin_bit_cast(bf16x8, pv);
      const __bf16* bbase = Bt + r * 128 + s * 32 + quad * 8;
      #pragma unroll
      for (int tc = 0; tc < 8; tc++){
        bf16x8 bfr = *(const bf16x8*)(bbase + (size_t)(tc * 16 + l15) * KDIM);
        accC[tc] = __builtin_amdgcn_mfma_f32_16x16x32_bf16(af, bfr, accC[tc], 0, 0, 0);
      }
    }
  }

  // epilogue: tanh, store bf16. C layout: col=l15, row=quad*4+reg
  #pragma unroll
  for (int tc = 0; tc < 8; tc++){
    #pragma unroll
    for (int reg = 0; reg < 4; reg++){
      int n2 = n0w + quad * 4 + reg;
      if (n2 < N_NODES){
        float v = tanhf(accC[tc][reg]);
        hout[(size_t)n2 * 128 + tc * 16 + l15] = (unsigned short)f2bf(v);
      }
    }
  }
}

// ---------------- fused head: mean -> dot W3 (f32 [512][2]) -> softmax -> f32 out ----------------
// One wave per node; lane holds dims (2*lane, 2*lane+1) of each relation block.

__global__ void fused_head(const unsigned* __restrict__ h2,
                           const int* __restrict__ ssrc,
                           const int* __restrict__ offs,
                           const float* __restrict__ W3f,
                           float* __restrict__ out){
  int n = blockIdx.x * 4 + (threadIdx.x >> 6);
  int lane = threadIdx.x & 63;
  float dA = 0.f, dB = 0.f;
  int ob = n * 4;
  #pragma unroll
  for (int r = 0; r < RREL; r++){
    int beg = iclamp(offs[ob + r], 0, N_EDGES);
    int end = iclamp(offs[ob + r + 1], beg, N_EDGES);
    float a0=0.f,a1=0.f,b0=0.f,b1=0.f,c0=0.f,c1=0.f,d0=0.f,d1=0.f;
    int i = beg;
    for (; i + 4 <= end; i += 4){
      int s0 = iclamp(ssrc[i],     0, N_NODES-1);
      int s1 = iclamp(ssrc[i + 1], 0, N_NODES-1);
      int s2 = iclamp(ssrc[i + 2], 0, N_NODES-1);
      int s3 = iclamp(ssrc[i + 3], 0, N_NODES-1);
      unsigned u0 = h2[(size_t)s0 * 64 + lane];
      unsigned u1 = h2[(size_t)s1 * 64 + lane];
      unsigned u2 = h2[(size_t)s2 * 64 + lane];
      unsigned u3 = h2[(size_t)s3 * 64 + lane];
      a0 += bflo(u0); a1 += bfhi(u0);
      b0 += bflo(u1); b1 += bfhi(u1);
      c0 += bflo(u2); c1 += bfhi(u2);
      d0 += bflo(u3); d1 += bfhi(u3);
    }
    for (; i < end; i++){
      unsigned u = h2[(size_t)iclamp(ssrc[i], 0, N_NODES-1) * 64 + lane];
      a0 += bflo(u); a1 += bfhi(u);
    }
    int cnt = end - beg;
    float sc = (cnt > 0) ? 1.0f / (float)cnt : 0.0f;
    float m0 = (a0 + b0 + c0 + d0) * sc, m1 = (a1 + b1 + c1 + d1) * sc;
    float4 wv = *(const float4*)(W3f + r * 256 + lane * 4);
    dA += m0 * wv.x + m1 * wv.z;
    dB += m0 * wv.y + m1 * wv.w;
  }
  #pragma unroll
  for (int m = 32; m >= 1; m >>= 1){
    dA += __shfl_xor(dA, m);
    dB += __shfl_xor(dB, m);
  }
  if (lane == 0){
    float mx = fmaxf(dA, dB);
    float e0 = __expf(dA - mx), e1 = __expf(dB - mx);
    float inv = 1.0f / (e0 + e1);
    *(float2*)(out + 2 * n) = (float2){e0 * inv, e1 * inv};            // softmax [N,2]
    *(float2*)(out + 2 * N_NODES + 2 * n) = (float2){dA, dB};          // logits  [N,2]
  }
}

// ---------------- launch ----------------

extern "C" void kernel_launch(void* const* d_in, const int* in_sizes, int n_in,
                              void* d_out, int out_size, void* d_ws, size_t ws_size,
                              hipStream_t stream){
  const float* x  = (const float*)d_in[0];
  const int* ei   = (const int*)d_in[1];
  const int* et   = (const int*)d_in[2];
  const float* W1 = (const float*)d_in[3];
  const float* W2 = (const float*)d_in[4];
  const float* W3 = (const float*)d_in[5];
  float* out = (float*)d_out;
  const int* src = ei;
  const int* dst = ei + N_EDGES;

  // workspace layout: ~61 MB total
  char* p = (char*)d_ws;
  auto alloc = [&](size_t bytes) -> char* {
    char* q = p; p += (bytes + 63) & ~(size_t)63; return q;
  };
  int* counts = (int*)alloc((size_t)NKEY * 4);          // reused as cursor
  int* cursor = counts;
  int* offs   = (int*)alloc((size_t)(NKEY + 1) * 4);
  int* bsums  = (int*)alloc(1024 * 4);
  int* ssrc   = (int*)alloc((size_t)N_EDGES * 4);
  unsigned short* Bt = (unsigned short*)alloc((size_t)DDIM * KDIM * 2);
  unsigned short* h1 = (unsigned short*)alloc((size_t)N_NODES * DDIM * 2);
  unsigned short* h2 = (unsigned short*)alloc((size_t)N_NODES * DDIM * 2);
  unsigned* xb = (unsigned*)h2;   // x-as-bf16 lives in h2's slot (dead until layer-2 output)

  // sort edges by (dst, relation)
  hipMemsetAsync(counts, 0, (size_t)NKEY * 4, stream);
  hist_kernel<<<N_EDGES / 256, 256, 0, stream>>>(dst, et, counts);
  int nb = (NKEY + 1023) / 1024;  // 391
  scan_local<<<nb, 1024, 0, stream>>>(counts, offs, bsums, NKEY);
  scan_sums<<<1, 1024, 0, stream>>>(bsums, nb);
  scan_add<<<nb, 1024, 0, stream>>>(offs, cursor, bsums, NKEY, N_EDGES);
  scatter_kernel<<<N_EDGES / 256, 256, 0, stream>>>(src, dst, et, cursor, ssrc);

  int fgrid = (N_NODES + 63) / 64;  // 1563

  // layer 1: x -> packed bf16, agg -> @W1 -> tanh -> h1
  convert_x<<<(N_NODES * 64) / 256, 256, 0, stream>>>(x, xb);
  transpose_w<<<(DDIM * KDIM) / 256, 256, 0, stream>>>(W1, Bt);
  fused_layer<<<fgrid, 256, 0, stream>>>(xb, ssrc, offs, (const __bf16*)Bt, h1);
  // layer 2: h1 -> h2 (xb dead from here on)
  transpose_w<<<(DDIM * KDIM) / 256, 256, 0, stream>>>(W2, Bt);
  fused_layer<<<fgrid, 256, 0, stream>>>((const unsigned*)h1, ssrc, offs, (const __bf16*)Bt, h2);
  // layer 3 + softmax head (f32 out)
  fused_head<<<N_NODES / 4, 256, 0, stream>>>((const unsigned*)h2, ssrc, offs, W3, out);
}